// Round 5
// baseline (492.132 us; speedup 1.0000x reference)
//
#include <hip/hip_runtime.h>

#define Q_INV (1.0f / 128.0f)

__device__ __forceinline__ float quant_comp_f(float v) {
    float f = floorf(v * 128.0f);
    f = fminf(fmaxf(f, -128.0f), 127.0f);
    int qi = (int)f;
    qi |= 1;
    return (float)qi * Q_INV;
}

// One block per image, 192 threads. Per-output fmaf chains are bit-identical
// to the R4 kernel (golden-matching): conv1 (ky,kx) asc; conv2 (ky,kx,ic)
// asc with ic innermost; bias as separate rounded add; relu after pool.
__global__ __launch_bounds__(192) void conv_fused_kernel(
    const float* __restrict__ x,
    const float* __restrict__ c1w, const float* __restrict__ c1b,
    const float* __restrict__ c2w, const float* __restrict__ c2b,
    const int* __restrict__ qflag,
    float* __restrict__ act)
{
    // union zone: pin[32][36] (1152 floats) then reused as rowmax1[6][28][17] (2856)
    __shared__ __align__(16) float shpool[2856];
    __shared__ float w1s[150];
    __shared__ float b1s[6];
    __shared__ float w2s[2400];
    __shared__ float b2s[16];
    __shared__ __align__(16) float mid[6][14][20];   // rows 0..13, cols 0..13 valid
    __shared__ float rowmax2[16][10][8];

    float (*pin)[36] = reinterpret_cast<float(*)[36]>(shpool);

    const int t = threadIdx.x;
    const int img = blockIdx.x;
    const bool q = (qflag[0] != 0);

    for (int i = t; i < 1152; i += 192) shpool[i] = 0.0f;
    if (t < 150) w1s[t] = c1w[t];
    if (t < 6) b1s[t] = c1b[t];
    for (int i = t; i < 2400; i += 192) w2s[i] = c2w[i];
    if (t < 16) b2s[t] = c2b[t];
    __syncthreads();

    const float* xi = x + (size_t)img * 784;
    for (int i = t; i < 784; i += 192) {
        float v = xi[i];
        if (q) v = quant_comp_f(v);
        pin[i / 28 + 2][i % 28 + 2] = v;
    }
    __syncthreads();

    // ---- conv1: t<168, thread=(c, conv-row oh), 28 points, row in registers
    float hmax1[14];
    if (t < 168) {
        const int c = t / 28, oh = t % 28;
        float acc[28];
        #pragma unroll
        for (int j = 0; j < 28; ++j) acc[j] = 0.0f;
        #pragma unroll
        for (int ky = 0; ky < 5; ++ky) {
            float rbf[32];
            const float4* pr = reinterpret_cast<const float4*>(&pin[oh + ky][0]);
            #pragma unroll
            for (int j = 0; j < 8; ++j) {
                float4 v = pr[j];
                rbf[4*j] = v.x; rbf[4*j+1] = v.y; rbf[4*j+2] = v.z; rbf[4*j+3] = v.w;
            }
            #pragma unroll
            for (int kx = 0; kx < 5; ++kx) {
                const float wv = w1s[c * 25 + ky * 5 + kx];
                #pragma unroll
                for (int ow = 0; ow < 28; ++ow)
                    acc[ow] = fmaf(rbf[ow + kx], wv, acc[ow]);
            }
        }
        const float bb = b1s[c];
        #pragma unroll
        for (int j = 0; j < 14; ++j) {
            float v0 = acc[2*j] + bb;
            float v1 = acc[2*j + 1] + bb;
            hmax1[j] = fmaxf(v0, v1);
        }
    }
    __syncthreads();   // all pin reads done; shpool becomes rowmax1[6][28][17]
    if (t < 168) {
        const int c = t / 28, oh = t % 28;
        #pragma unroll
        for (int j = 0; j < 14; ++j) shpool[(c * 28 + oh) * 17 + j] = hmax1[j];
    }
    __syncthreads();
    // vertical pool + relu + quant -> mid
    if (t < 84) {
        const int c = t / 14, ph = t % 14;
        #pragma unroll
        for (int j = 0; j < 14; ++j) {
            float m = fmaxf(shpool[(c * 28 + 2 * ph) * 17 + j],
                            shpool[(c * 28 + 2 * ph + 1) * 17 + j]);
            m = fmaxf(m, 0.0f);
            if (q) m = quant_comp_f(m);
            mid[c][ph][j] = m;
        }
    }
    __syncthreads();

    // ---- conv2: t<160, thread=(c, conv-row oh), 10 points, 6-ch row-set in regs
    float hmax2[5];
    if (t < 160) {
        const int c = t / 10, oh = t % 10;
        float acc[10];
        #pragma unroll
        for (int j = 0; j < 10; ++j) acc[j] = 0.0f;
        #pragma unroll
        for (int ky = 0; ky < 5; ++ky) {
            float rb[6][16];
            #pragma unroll
            for (int ic = 0; ic < 6; ++ic) {
                const float4* mr = reinterpret_cast<const float4*>(&mid[ic][oh + ky][0]);
                #pragma unroll
                for (int j2 = 0; j2 < 4; ++j2) {
                    float4 v = mr[j2];
                    rb[ic][4*j2] = v.x; rb[ic][4*j2+1] = v.y;
                    rb[ic][4*j2+2] = v.z; rb[ic][4*j2+3] = v.w;
                }
            }
            #pragma unroll
            for (int kx = 0; kx < 5; ++kx) {
                #pragma unroll
                for (int ic = 0; ic < 6; ++ic) {
                    const float wv = w2s[(c * 6 + ic) * 25 + ky * 5 + kx];
                    #pragma unroll
                    for (int ow = 0; ow < 10; ++ow)
                        acc[ow] = fmaf(rb[ic][ow + kx], wv, acc[ow]);
                }
            }
        }
        const float bb = b2s[c];
        #pragma unroll
        for (int j = 0; j < 5; ++j) {
            float v0 = acc[2*j] + bb;
            float v1 = acc[2*j + 1] + bb;
            hmax2[j] = fmaxf(v0, v1);
        }
    }
    // rowmax2 is a distinct buffer; only a write->read barrier needed
    if (t < 160) {
        const int c = t / 10, oh = t % 10;
        #pragma unroll
        for (int j = 0; j < 5; ++j) rowmax2[c][oh][j] = hmax2[j];
    }
    __syncthreads();
    if (t < 80) {
        const int c = t / 5, ph = t % 5;
        float* ao = act + (size_t)img * 400;
        #pragma unroll
        for (int j = 0; j < 5; ++j) {
            float m = fmaxf(rowmax2[c][2 * ph][j], rowmax2[c][2 * ph + 1][j]);
            m = fmaxf(m, 0.0f);
            if (q) m = quant_comp_f(m);
            ao[c * 25 + ph * 5 + j] = m;
        }
    }
}

// 16 images per block; dual-output threads (2 independent chains -> ILP 2,
// halves a-vector LDS reads). Per-output chain identical to R4.
__global__ __launch_bounds__(256) void fc_fused_kernel(
    const float* __restrict__ act,
    const float* __restrict__ w1, const float* __restrict__ b1,
    const float* __restrict__ w2, const float* __restrict__ b2,
    const float* __restrict__ w3, const float* __restrict__ b3,
    const int* __restrict__ qflag,
    float* __restrict__ out, int B)
{
    __shared__ __align__(16) float a0[16][404];
    __shared__ __align__(16) float a1[16][124];
    __shared__ __align__(16) float a2[16][88];

    const int t = threadIdx.x;
    const bool q = (qflag[0] != 0);
    const int base = blockIdx.x * 16;

    for (int i = t; i < 16 * 400; i += 256) {
        const int im = i / 400, k = i % 400;
        if (base + im < B) a0[im][k] = act[(size_t)(base + im) * 400 + k];
    }
    __syncthreads();

    const int im = t & 15;
    const int grp = t >> 4;

    // fc1: 120 outs, k=400; rounds of 32 outs (2 per thread-group)
    #pragma unroll
    for (int r = 0; r < 4; ++r) {
        const int o0 = 32 * r + 2 * grp;
        if (o0 < 120) {
            const float4* wr0 = reinterpret_cast<const float4*>(w1 + o0 * 400);
            const float4* wr1 = reinterpret_cast<const float4*>(w1 + (o0 + 1) * 400);
            const float4* ar = reinterpret_cast<const float4*>(&a0[im][0]);
            float acc0 = 0.0f, acc1 = 0.0f;
            #pragma unroll 4
            for (int kk = 0; kk < 100; ++kk) {
                const float4 av = ar[kk];
                const float4 wv0 = wr0[kk];
                const float4 wv1 = wr1[kk];
                acc0 = fmaf(av.x, wv0.x, acc0); acc0 = fmaf(av.y, wv0.y, acc0);
                acc0 = fmaf(av.z, wv0.z, acc0); acc0 = fmaf(av.w, wv0.w, acc0);
                acc1 = fmaf(av.x, wv1.x, acc1); acc1 = fmaf(av.y, wv1.y, acc1);
                acc1 = fmaf(av.z, wv1.z, acc1); acc1 = fmaf(av.w, wv1.w, acc1);
            }
            float v0 = acc0 + b1[o0];
            float v1 = acc1 + b1[o0 + 1];
            v0 = fmaxf(v0, 0.0f); v1 = fmaxf(v1, 0.0f);
            a1[im][o0] = q ? quant_comp_f(v0) : v0;
            a1[im][o0 + 1] = q ? quant_comp_f(v1) : v1;
        }
    }
    __syncthreads();

    // fc2: 84 outs, k=120
    #pragma unroll
    for (int r = 0; r < 3; ++r) {
        const int o0 = 32 * r + 2 * grp;
        if (o0 < 84) {
            const float4* wr0 = reinterpret_cast<const float4*>(w2 + o0 * 120);
            const float4* wr1 = reinterpret_cast<const float4*>(w2 + (o0 + 1) * 120);
            const float4* ar = reinterpret_cast<const float4*>(&a1[im][0]);
            float acc0 = 0.0f, acc1 = 0.0f;
            #pragma unroll 3
            for (int kk = 0; kk < 30; ++kk) {
                const float4 av = ar[kk];
                const float4 wv0 = wr0[kk];
                const float4 wv1 = wr1[kk];
                acc0 = fmaf(av.x, wv0.x, acc0); acc0 = fmaf(av.y, wv0.y, acc0);
                acc0 = fmaf(av.z, wv0.z, acc0); acc0 = fmaf(av.w, wv0.w, acc0);
                acc1 = fmaf(av.x, wv1.x, acc1); acc1 = fmaf(av.y, wv1.y, acc1);
                acc1 = fmaf(av.z, wv1.z, acc1); acc1 = fmaf(av.w, wv1.w, acc1);
            }
            float v0 = acc0 + b2[o0];
            float v1 = acc1 + b2[o0 + 1];
            v0 = fmaxf(v0, 0.0f); v1 = fmaxf(v1, 0.0f);
            a2[im][o0] = q ? quant_comp_f(v0) : v0;
            a2[im][o0 + 1] = q ? quant_comp_f(v1) : v1;
        }
    }
    __syncthreads();

    // fc3: 10 outs, k=84
    {
        const int o0 = 2 * grp;
        if (o0 < 10) {
            const float4* wr0 = reinterpret_cast<const float4*>(w3 + o0 * 84);
            const float4* wr1 = reinterpret_cast<const float4*>(w3 + (o0 + 1) * 84);
            const float4* ar = reinterpret_cast<const float4*>(&a2[im][0]);
            float acc0 = 0.0f, acc1 = 0.0f;
            #pragma unroll
            for (int kk = 0; kk < 21; ++kk) {
                const float4 av = ar[kk];
                const float4 wv0 = wr0[kk];
                const float4 wv1 = wr1[kk];
                acc0 = fmaf(av.x, wv0.x, acc0); acc0 = fmaf(av.y, wv0.y, acc0);
                acc0 = fmaf(av.z, wv0.z, acc0); acc0 = fmaf(av.w, wv0.w, acc0);
                acc1 = fmaf(av.x, wv1.x, acc1); acc1 = fmaf(av.y, wv1.y, acc1);
                acc1 = fmaf(av.z, wv1.z, acc1); acc1 = fmaf(av.w, wv1.w, acc1);
            }
            if (base + im < B) {
                out[(size_t)(base + im) * 10 + o0] = acc0 + b3[o0];
                out[(size_t)(base + im) * 10 + o0 + 1] = acc1 + b3[o0 + 1];
            }
        }
    }
}

extern "C" void kernel_launch(void* const* d_in, const int* in_sizes, int n_in,
                              void* d_out, int out_size, void* d_ws, size_t ws_size,
                              hipStream_t stream) {
    const float* x     = (const float*)d_in[0];
    const float* c1w   = (const float*)d_in[1];
    const float* c1b   = (const float*)d_in[2];
    const float* c2w   = (const float*)d_in[3];
    const float* c2b   = (const float*)d_in[4];
    const float* fc1w  = (const float*)d_in[5];
    const float* fc1b  = (const float*)d_in[6];
    const float* fc2w  = (const float*)d_in[7];
    const float* fc2b  = (const float*)d_in[8];
    const float* fc3w  = (const float*)d_in[9];
    const float* fc3b  = (const float*)d_in[10];
    const int*   qflag = (const int*)d_in[11];
    float* out = (float*)d_out;

    const int B = in_sizes[0] / 784;
    float* act = (float*)d_ws;  // [B,400]

    conv_fused_kernel<<<B, 192, 0, stream>>>(x, c1w, c1b, c2w, c2b, qflag, act);

    const int nblk = (B + 15) / 16;
    fc_fused_kernel<<<nblk, 256, 0, stream>>>(act, fc1w, fc1b, fc2w, fc2b,
                                              fc3w, fc3b, qflag, out, B);
}